// Round 8
// baseline (306.873 us; speedup 1.0000x reference)
//
#include <hip/hip_runtime.h>

#define BB 2
#define RR 2
#define NN 50000
#define EE 500000
#define DD 128
#define NSLOT 4
#define BSH 6                 // dst >> 6 -> bucket
#define BSZ 64                // dsts per bucket
#define NB 782                // ceil(NN/64)
#define FT 8192               // edges per fill block (keeps ~42B write runs)
#define FBLK 62               // ceil(EE/FT)
#define SCAP 2048             // sort LDS capacity (bucket mean 640, std 25)
#define DSTR 50048            // per-slot dofs stride
#define NPASS 8
#define PRNG 6250             // src range per pass; window 6250*512B=3.2MB < 4MB L2/XCD

// ---- layout A (proven-safe, ~21.7 MB): single pre[NN][DD] ----
#define A_PRE  0u
#define A_REC  12800000u
#define A_CNT  20800000u
#define A_OFS  20812544u
#define A_CUR  20825088u
#define A_DOF  20837632u
#define A_WT   21638400u

// ---- layout B (~34.5 MB): pre_both[NN][2][DD] + fused gather ----
#define B_PRE  0u
#define B_REC  25600000u
#define B_CNT  33600000u
#define B_OFS  33612544u
#define B_CUR  33625088u
#define B_DOF  33637632u
#define B_WT   34438400u
#define B_TOTAL 34503936u

typedef __attribute__((ext_vector_type(8))) short bf16x8;
typedef __attribute__((ext_vector_type(4))) float f32x4;

__device__ __forceinline__ unsigned short f2bf(float f) {
    unsigned int u = __float_as_uint(f);
    u += 0x7fffu + ((u >> 16) & 1u);   // RNE
    return (unsigned short)(u >> 16);
}

__device__ __forceinline__ bf16x8 pack8(float4 a, float4 b) {
    bf16x8 r;
    r[0] = (short)f2bf(a.x); r[1] = (short)f2bf(a.y);
    r[2] = (short)f2bf(a.z); r[3] = (short)f2bf(a.w);
    r[4] = (short)f2bf(b.x); r[5] = (short)f2bf(b.y);
    r[6] = (short)f2bf(b.z); r[7] = (short)f2bf(b.w);
    return r;
}

// ---------------- W transpose+cast: w[R][K][N] f32 -> wt[R][N][K] bf16
__global__ __launch_bounds__(256) void wprep_kernel(
    const float* __restrict__ w, unsigned short* __restrict__ wt)
{
    int idx = blockIdx.x * 256 + threadIdx.x;
    if (idx >= RR * DD * DD) return;
    int r = idx >> 14;
    int k = (idx >> 7) & (DD - 1);
    int n = idx & (DD - 1);
    wt[((size_t)r * DD + n) * DD + k] = f2bf(w[idx]);
}

// ---------------- GEMM (layout A fallback): pre = bf16( x @ W ), one relation
template <int RST>
__global__ __launch_bounds__(256) void gemm_mfma_kernel(
    const float* __restrict__ x,
    const unsigned short* __restrict__ wt,
    unsigned short* __restrict__ pre)
{
    const int tid = threadIdx.x;
    const int w = tid >> 6, lane = tid & 63;
    const int wr = w >> 1, wc = w & 1;
    const int lq = lane >> 4, lr = lane & 15;
    const int row0 = blockIdx.x * 128;

    f32x4 acc[4][4] = {};

    #pragma unroll
    for (int ks = 0; ks < 4; ++ks) {
        const int k0 = ks * 32 + lq * 8;
        bf16x8 a[4], b[4];
        #pragma unroll
        for (int mi = 0; mi < 4; ++mi) {
            int row = row0 + wr * 64 + mi * 16 + lr;
            float4 v0 = make_float4(0.f, 0.f, 0.f, 0.f);
            float4 v1 = make_float4(0.f, 0.f, 0.f, 0.f);
            if (row < NN) {
                const float* p = x + (size_t)row * DD + k0;
                v0 = *(const float4*)p;
                v1 = *(const float4*)(p + 4);
            }
            a[mi] = pack8(v0, v1);
        }
        #pragma unroll
        for (int ni = 0; ni < 4; ++ni) {
            int n = wc * 64 + ni * 16 + lr;
            b[ni] = *(const bf16x8*)(wt + (size_t)n * DD + k0);
        }
        #pragma unroll
        for (int mi = 0; mi < 4; ++mi)
            #pragma unroll
            for (int ni = 0; ni < 4; ++ni)
                acc[mi][ni] = __builtin_amdgcn_mfma_f32_16x16x32_bf16(
                    a[mi], b[ni], acc[mi][ni], 0, 0, 0);
    }

    #pragma unroll
    for (int mi = 0; mi < 4; ++mi) {
        #pragma unroll
        for (int q = 0; q < 4; ++q) {
            int row = row0 + wr * 64 + mi * 16 + lq * 4 + q;
            if (row < NN) {
                #pragma unroll
                for (int ni = 0; ni < 4; ++ni) {
                    int col = wc * 64 + ni * 16 + lr;
                    pre[(size_t)row * RST + col] = f2bf(acc[mi][ni][q]);
                }
            }
        }
    }
}

// ---------------- GEMM (layout B): BOTH relations in one pass over x.
__global__ __launch_bounds__(512) void gemm_mfma_dual_kernel(
    const float* __restrict__ x,            // [NN][DD] f32
    const unsigned short* __restrict__ wt,  // [256 n][DD k] bf16 (W0|W1)
    unsigned short* __restrict__ pre)       // [NN][2*DD] bf16
{
    const int tid = threadIdx.x;
    const int w = tid >> 6, lane = tid & 63;
    const int wr = w >> 2, wc = w & 3;
    const int lq = lane >> 4, lr = lane & 15;
    const int row0 = blockIdx.x * 128;

    f32x4 acc[4][4] = {};

    #pragma unroll
    for (int ks = 0; ks < 4; ++ks) {
        const int k0 = ks * 32 + lq * 8;
        bf16x8 a[4], b[4];
        #pragma unroll
        for (int mi = 0; mi < 4; ++mi) {
            int row = row0 + wr * 64 + mi * 16 + lr;
            float4 v0 = make_float4(0.f, 0.f, 0.f, 0.f);
            float4 v1 = make_float4(0.f, 0.f, 0.f, 0.f);
            if (row < NN) {
                const float* p = x + (size_t)row * DD + k0;
                v0 = *(const float4*)p;
                v1 = *(const float4*)(p + 4);
            }
            a[mi] = pack8(v0, v1);
        }
        #pragma unroll
        for (int ni = 0; ni < 4; ++ni) {
            int n = wc * 64 + ni * 16 + lr;      // 0..255 -> W0|W1
            b[ni] = *(const bf16x8*)(wt + (size_t)n * DD + k0);
        }
        #pragma unroll
        for (int mi = 0; mi < 4; ++mi)
            #pragma unroll
            for (int ni = 0; ni < 4; ++ni)
                acc[mi][ni] = __builtin_amdgcn_mfma_f32_16x16x32_bf16(
                    a[mi], b[ni], acc[mi][ni], 0, 0, 0);
    }

    #pragma unroll
    for (int mi = 0; mi < 4; ++mi) {
        #pragma unroll
        for (int q = 0; q < 4; ++q) {
            int row = row0 + wr * 64 + mi * 16 + lq * 4 + q;
            if (row < NN) {
                #pragma unroll
                for (int ni = 0; ni < 4; ++ni) {
                    int col = wc * 64 + ni * 16 + lr;
                    pre[(size_t)row * (2 * DD) + col] = f2bf(acc[mi][ni][q]);
                }
            }
        }
    }
}

// ---------------- hist: LDS-privatized bucket histogram
__global__ __launch_bounds__(256) void hist_kernel(
    const int* __restrict__ edst, int* __restrict__ counts)
{
    __shared__ int h[NB];
    for (int i = threadIdx.x; i < NB; i += 256) h[i] = 0;
    __syncthreads();
    const int slot = blockIdx.y;
    const int* ed = edst + (size_t)slot * EE;
    for (int e = blockIdx.x * 256 + threadIdx.x; e < EE; e += 128 * 256)
        atomicAdd(&h[ed[e] >> BSH], 1);
    __syncthreads();
    int* c = counts + slot * NB;
    for (int i = threadIdx.x; i < NB; i += 256) {
        int v = h[i];
        if (v) atomicAdd(&c[i], v);
    }
}

// ---------------- scan: per-slot exclusive scan of NB bucket counts
__global__ __launch_bounds__(1024) void scan_kernel(
    const int* __restrict__ counts, int* __restrict__ offsets,
    int* __restrict__ cursor)
{
    __shared__ int s[1024];
    const int slot = blockIdx.x;
    int v = (threadIdx.x < NB) ? counts[slot * NB + threadIdx.x] : 0;
    s[threadIdx.x] = v;
    for (int o = 1; o < 1024; o <<= 1) {
        __syncthreads();
        int t = (threadIdx.x >= o) ? s[threadIdx.x - o] : 0;
        __syncthreads();
        s[threadIdx.x] += t;
    }
    __syncthreads();
    if (threadIdx.x < NB) {
        int incl = s[threadIdx.x];
        offsets[slot * 784 + threadIdx.x + 1] = incl;
        cursor[slot * NB + threadIdx.x] = incl - v;
    }
    if (threadIdx.x == 0) offsets[slot * 784] = 0;
}

// ---------------- fill: 1024 threads (16 waves) for latency hiding
// rec = src[15:0] | dstLocal[21:16] | valq[31:22]
__global__ __launch_bounds__(1024) void fill_kernel(
    const int* __restrict__ esrc, const int* __restrict__ edst,
    const float* __restrict__ ev, int* __restrict__ cursor,
    unsigned int* __restrict__ recs)
{
    __shared__ int lh[NB];
    __shared__ int lbase[NB];
    const int slot = blockIdx.y;
    const size_t eb = (size_t)slot * EE;
    const int e0 = blockIdx.x * FT;

    for (int i = threadIdx.x; i < NB; i += 1024) lh[i] = 0;
    __syncthreads();
    for (int t = 0; t < FT; t += 1024) {
        int e = e0 + t + threadIdx.x;
        if (e < EE) atomicAdd(&lh[edst[eb + e] >> BSH], 1);
    }
    __syncthreads();
    for (int i = threadIdx.x; i < NB; i += 1024) {
        int c = lh[i];
        lbase[i] = c ? atomicAdd(&cursor[slot * NB + i], c) : 0;
        lh[i] = 0;    // reuse as local cursor
    }
    __syncthreads();
    for (int t = 0; t < FT; t += 1024) {
        int e = e0 + t + threadIdx.x;
        if (e < EE) {
            int d = edst[eb + e];
            int bk = d >> BSH;
            unsigned vq = (unsigned)__builtin_rintf(ev[eb + e] * 1023.0f);
            unsigned rec = (unsigned)esrc[eb + e] |
                           ((unsigned)(d & (BSZ - 1)) << 16) | (vq << 22);
            int p = lbase[bk] + atomicAdd(&lh[bk], 1);
            recs[eb + p] = rec;
        }
    }
}

// ---------------- sort: counting-sort by dst, then per-dst insertion by src
__global__ __launch_bounds__(256) void sort_kernel(
    unsigned int* __restrict__ recs, const int* __restrict__ offsets,
    int* __restrict__ dofs)
{
    __shared__ unsigned int lrec[SCAP];
    __shared__ unsigned int srec[SCAP];
    __shared__ int cnt[BSZ];
    __shared__ int cur[BSZ];
    __shared__ int sstart[BSZ];
    const int bk = blockIdx.x, slot = blockIdx.y;
    unsigned int* rp = recs + (size_t)slot * EE;
    const int s = offsets[slot * 784 + bk], e = offsets[slot * 784 + bk + 1];
    const int n = e - s;

    for (int i = threadIdx.x; i < n; i += 256) lrec[i] = rp[s + i];
    if (threadIdx.x < BSZ) cnt[threadIdx.x] = 0;
    __syncthreads();
    for (int i = threadIdx.x; i < n; i += 256)
        atomicAdd(&cnt[(lrec[i] >> 16) & (BSZ - 1)], 1);
    __syncthreads();
    if (threadIdx.x < 64) {
        int v = cnt[threadIdx.x];
        int incl = v;
        #pragma unroll
        for (int o = 1; o < 64; o <<= 1) {
            int t = __shfl_up(incl, o, 64);
            if (threadIdx.x >= o) incl += t;
        }
        int excl = incl - v;
        cur[threadIdx.x] = excl;
        sstart[threadIdx.x] = excl;
        dofs[(size_t)slot * DSTR + bk * BSZ + threadIdx.x] = s + excl;
    }
    __syncthreads();
    for (int i = threadIdx.x; i < n; i += 256) {
        unsigned r = lrec[i];
        int p = atomicAdd(&cur[(r >> 16) & (BSZ - 1)], 1);
        srec[p] = r;
    }
    __syncthreads();
    // per-dst insertion sort by src (segments avg ~10)
    if (threadIdx.x < 64) {
        const int a = sstart[threadIdx.x];
        const int m = cnt[threadIdx.x];
        for (int j = 1; j < m; ++j) {
            unsigned key = srec[a + j];
            unsigned ks = key & 0xffffu;
            int k = j - 1;
            while (k >= 0 && (srec[a + k] & 0xffffu) > ks) {
                srec[a + k + 1] = srec[a + k];
                --k;
            }
            srec[a + k + 1] = key;
        }
    }
    __syncthreads();
    for (int i = threadIdx.x; i < n; i += 256) rp[s + i] = srec[i];
}

// ---------------- gather cores
#define DEQ (1.0f / 1023.0f)
#define LO16(u) __uint_as_float((u) << 16)
#define HI16(u) __uint_as_float((u) & 0xffff0000u)

// SH: log2(row stride in elements); OFF: element offset within row.
template <int SH, int OFF>
__device__ __forceinline__ void gacc(const unsigned short* __restrict__ pre,
                                     const unsigned int* __restrict__ rp,
                                     unsigned i, unsigned e, unsigned lane2,
                                     float& acc0, float& acc1)
{
    const unsigned base = (unsigned)OFF + lane2;
    for (; i + 8 <= e; i += 8) {
        unsigned q[8], u[8];
        #pragma unroll
        for (int j = 0; j < 8; ++j) q[j] = rp[i + j];
        #pragma unroll
        for (int j = 0; j < 8; ++j)
            u[j] = *(const unsigned*)(pre + (((q[j] & 0xffffu) << SH) + base));
        #pragma unroll
        for (int j = 0; j < 8; ++j) {
            float s = (float)(q[j] >> 22) * DEQ;
            acc0 = fmaf(s, LO16(u[j]), acc0);
            acc1 = fmaf(s, HI16(u[j]), acc1);
        }
    }
    for (; i < e; ++i) {
        unsigned q0 = rp[i];
        unsigned u0 = *(const unsigned*)(pre + (((q0 & 0xffffu) << SH) + base));
        float s0 = (float)(q0 >> 22) * DEQ;
        acc0 = fmaf(s0, LO16(u0), acc0); acc1 = fmaf(s0, HI16(u0), acc1);
    }
}

// layout A: one wave per dst row, single relation
template <int FINAL>
__global__ __launch_bounds__(256) void gather_kernel(
    const unsigned short* __restrict__ pre, const unsigned int* __restrict__ rp,
    const int* __restrict__ dofs, const float* __restrict__ bias,
    float* __restrict__ out)
{
    const int d = blockIdx.x * 4 + (threadIdx.x >> 6);
    const unsigned lane2 = (threadIdx.x & 63) * 2;
    const unsigned i = dofs[d], e = dofs[d + 1];

    float2* o = (float2*)(out + (size_t)d * DD + lane2);
    float2 pv;
    float b0, b1;
    if (FINAL) {
        pv = *o;
        b0 = bias[lane2]; b1 = bias[lane2 + 1];
    }

    float acc0 = 0.f, acc1 = 0.f;
    gacc<7, 0>(pre, rp, i, e, lane2, acc0, acc1);

    if (FINAL) {
        pv.x = fmaxf(pv.x + acc0 + b0, 0.f);
        pv.y = fmaxf(pv.y + acc1 + b1, 0.f);
        *o = pv;
    } else {
        *o = make_float2(acc0, acc1);
    }
}

// layout B: one wave per dst, both relations, synchronized src-range sweep.
// Lists are sorted by src; pass p touches rows [p*PRNG,(p+1)*PRNG) so the
// concurrently-active read window is 3.2 MB -> L2-resident per XCD.
__global__ __launch_bounds__(256) void gather_dual_kernel(
    const unsigned short* __restrict__ preb,        // [NN][2][DD]
    const unsigned int* __restrict__ rp0, const unsigned int* __restrict__ rp1,
    const int* __restrict__ dofs0, const int* __restrict__ dofs1,
    const float* __restrict__ bias, float* __restrict__ out)
{
    const int d = blockIdx.x * 4 + (threadIdx.x >> 6);
    const unsigned lane2 = (threadIdx.x & 63) * 2;
    unsigned i0 = dofs0[d];
    const unsigned e0 = dofs0[d + 1];
    unsigned i1 = dofs1[d];
    const unsigned e1 = dofs1[d + 1];

    float acc0 = 0.f, acc1 = 0.f;
    unsigned q0 = 0, q1 = 0;
    bool v0 = i0 < e0, v1 = i1 < e1;
    if (v0) q0 = rp0[i0];
    if (v1) q1 = rp1[i1];

    #pragma unroll 1
    for (unsigned p = 1; p <= NPASS; ++p) {
        const unsigned bound = p * PRNG;
        bool r0 = v0 && (q0 & 0xffffu) < bound;
        bool r1 = v1 && (q1 & 0xffffu) < bound;
        while (r0 || r1) {           // wave-uniform control flow
            if (r0) {
                unsigned u0 = *(const unsigned*)(preb + (((q0 & 0xffffu) << 8) + lane2));
                float s0 = (float)(q0 >> 22) * DEQ;
                ++i0;
                v0 = i0 < e0;
                if (v0) q0 = rp0[i0];
                acc0 = fmaf(s0, LO16(u0), acc0);
                acc1 = fmaf(s0, HI16(u0), acc1);
            }
            if (r1) {
                unsigned u1 = *(const unsigned*)(preb + (((q1 & 0xffffu) << 8) + DD + lane2));
                float s1 = (float)(q1 >> 22) * DEQ;
                ++i1;
                v1 = i1 < e1;
                if (v1) q1 = rp1[i1];
                acc0 = fmaf(s1, LO16(u1), acc0);
                acc1 = fmaf(s1, HI16(u1), acc1);
            }
            r0 = v0 && (q0 & 0xffffu) < bound;
            r1 = v1 && (q1 & 0xffffu) < bound;
        }
    }

    float2 pv;
    pv.x = fmaxf(acc0 + bias[lane2], 0.f);
    pv.y = fmaxf(acc1 + bias[lane2 + 1], 0.f);
    *(float2*)(out + (size_t)d * DD + lane2) = pv;
}

extern "C" void kernel_launch(void* const* d_in, const int* in_sizes, int n_in,
                              void* d_out, int out_size, void* d_ws, size_t ws_size,
                              hipStream_t stream) {
    const float* x     = (const float*)d_in[0];
    const float* eval_ = (const float*)d_in[1];
    const float* w     = (const float*)d_in[2];
    const float* bias  = (const float*)d_in[3];
    const int*   esrc  = (const int*)d_in[4];
    const int*   edst  = (const int*)d_in[5];
    float* out = (float*)d_out;

    const bool useB = (ws_size >= (size_t)B_TOTAL);   // constant per harness

    char* ws = (char*)d_ws;
    unsigned short* pre     = (unsigned short*)(ws + (useB ? B_PRE : A_PRE));
    unsigned int*   recs    = (unsigned int*)(ws + (useB ? B_REC : A_REC));
    int*            counts  = (int*)(ws + (useB ? B_CNT : A_CNT));
    int*            offsets = (int*)(ws + (useB ? B_OFS : A_OFS));
    int*            cursor  = (int*)(ws + (useB ? B_CUR : A_CUR));
    int*            dofs    = (int*)(ws + (useB ? B_DOF : A_DOF));
    unsigned short* wt      = (unsigned short*)(ws + (useB ? B_WT : A_WT));

    const dim3 blk(256);

    hipMemsetAsync(counts, 0, NSLOT * NB * sizeof(int), stream);
    wprep_kernel<<<(RR * DD * DD + 255) / 256, blk, 0, stream>>>(w, wt);

    // CSR build (edge-only, once for all 4 slots)
    hist_kernel<<<dim3(128, NSLOT), blk, 0, stream>>>(edst, counts);
    scan_kernel<<<dim3(NSLOT), dim3(1024), 0, stream>>>(counts, offsets, cursor);
    fill_kernel<<<dim3(FBLK, NSLOT), dim3(1024), 0, stream>>>(
        esrc, edst, eval_, cursor, recs);
    sort_kernel<<<dim3(NB, NSLOT), blk, 0, stream>>>(recs, offsets, dofs);

    const dim3 gemm_grid((NN + 127) / 128);
    const dim3 gath_grid(NN / 4);

    if (useB) {
        for (int b = 0; b < BB; ++b) {
            const int s0 = b * RR, s1 = b * RR + 1;
            gemm_mfma_dual_kernel<<<gemm_grid, dim3(512), 0, stream>>>(
                x + (size_t)b * NN * DD, wt, pre);
            gather_dual_kernel<<<gath_grid, blk, 0, stream>>>(
                pre, recs + (size_t)s0 * EE, recs + (size_t)s1 * EE,
                dofs + (size_t)s0 * DSTR, dofs + (size_t)s1 * DSTR,
                bias, out + (size_t)b * NN * DD);
        }
    } else {
        for (int b = 0; b < BB; ++b) {
            for (int r = 0; r < RR; ++r) {
                const int slot = b * RR + r;
                gemm_mfma_kernel<DD><<<gemm_grid, blk, 0, stream>>>(
                    x + (size_t)b * NN * DD, wt + (size_t)r * DD * DD, pre);
                if (r == 0)
                    gather_kernel<0><<<gath_grid, blk, 0, stream>>>(
                        pre, recs + (size_t)slot * EE, dofs + (size_t)slot * DSTR,
                        bias, out + (size_t)b * NN * DD);
                else
                    gather_kernel<1><<<gath_grid, blk, 0, stream>>>(
                        pre, recs + (size_t)slot * EE, dofs + (size_t)slot * DSTR,
                        bias, out + (size_t)b * NN * DD);
            }
        }
    }
}

// Round 9
// 191.216 us; speedup vs baseline: 1.6048x; 1.6048x over previous
//
#include <hip/hip_runtime.h>

#define BB 2
#define RR 2
#define NN 50000
#define EE 500000
#define DD 128
#define NSLOT 4
#define BSH 6                 // dst >> 6 -> bucket
#define BSZ 64                // dsts per bucket
#define NB 782                // ceil(NN/64)
#define FT 8192               // edges per fill block (keeps ~42B write runs)
#define FBLK 62               // ceil(EE/FT)
#define SCAP 2048             // sort LDS capacity (bucket mean 640, std 25)
#define DSTR 50048            // per-slot dofs stride

// ---- workspace layout (bytes), total ~21.7 MB (proven safe) ----
#define XB_OFF  0u            // bf16 xb[NN][DD]             12,800,000
#define REC_OFF 12800000u     // uint recs[NSLOT][EE]         8,000,000
#define CNT_OFF 20800000u     // int counts[NSLOT][NB]           12,512
#define OFS_OFF 20812544u     // int offsets[NSLOT][784]         12,544
#define CUR_OFF 20825088u     // int cursor[NSLOT][NB]           12,512
#define DOF_OFF 20837632u     // int dofs[NSLOT][DSTR]          800,768
#define WT_OFF  21638400u     // bf16 wt2[128 n][256 k']         65,536

typedef __attribute__((ext_vector_type(8))) short bf16x8;
typedef __attribute__((ext_vector_type(4))) float f32x4;

__device__ __forceinline__ unsigned short f2bf(float f) {
    unsigned int u = __float_as_uint(f);
    u += 0x7fffu + ((u >> 16) & 1u);   // RNE
    return (unsigned short)(u >> 16);
}

__device__ __forceinline__ bf16x8 pack8(float4 a, float4 b) {
    bf16x8 r;
    r[0] = (short)f2bf(a.x); r[1] = (short)f2bf(a.y);
    r[2] = (short)f2bf(a.z); r[3] = (short)f2bf(a.w);
    r[4] = (short)f2bf(b.x); r[5] = (short)f2bf(b.y);
    r[6] = (short)f2bf(b.z); r[7] = (short)f2bf(b.w);
    return r;
}

// ---------------- W prep: w[R][K][N] f32 -> wt2[n][r*128+k] bf16
// (B-matrix for the K=256 fused GEMM: [W0;W1] stored [n][k'] )
__global__ __launch_bounds__(256) void wprep_kernel(
    const float* __restrict__ w, unsigned short* __restrict__ wt2)
{
    int idx = blockIdx.x * 256 + threadIdx.x;       // RR*DD*DD = 32768
    if (idx >= RR * DD * DD) return;
    int r = idx >> 14;
    int k = (idx >> 7) & (DD - 1);
    int n = idx & (DD - 1);
    wt2[(size_t)n * 256 + r * DD + k] = f2bf(w[idx]);
}

// ---------------- cast one batch of x to bf16
__global__ __launch_bounds__(256) void cast_kernel(
    const float* __restrict__ x, unsigned short* __restrict__ xb)
{
    int i8 = (blockIdx.x * 256 + threadIdx.x) * 8;
    if (i8 >= NN * DD) return;
    float4 v0 = *(const float4*)&x[i8];
    float4 v1 = *(const float4*)&x[i8 + 4];
    *(bf16x8*)&xb[i8] = pack8(v0, v1);
}

// ---------------- hist: LDS-privatized bucket histogram
__global__ __launch_bounds__(256) void hist_kernel(
    const int* __restrict__ edst, int* __restrict__ counts)
{
    __shared__ int h[NB];
    for (int i = threadIdx.x; i < NB; i += 256) h[i] = 0;
    __syncthreads();
    const int slot = blockIdx.y;
    const int* ed = edst + (size_t)slot * EE;
    for (int e = blockIdx.x * 256 + threadIdx.x; e < EE; e += 128 * 256)
        atomicAdd(&h[ed[e] >> BSH], 1);
    __syncthreads();
    int* c = counts + slot * NB;
    for (int i = threadIdx.x; i < NB; i += 256) {
        int v = h[i];
        if (v) atomicAdd(&c[i], v);
    }
}

// ---------------- scan: per-slot exclusive scan of NB bucket counts
__global__ __launch_bounds__(1024) void scan_kernel(
    const int* __restrict__ counts, int* __restrict__ offsets,
    int* __restrict__ cursor)
{
    __shared__ int s[1024];
    const int slot = blockIdx.x;
    int v = (threadIdx.x < NB) ? counts[slot * NB + threadIdx.x] : 0;
    s[threadIdx.x] = v;
    for (int o = 1; o < 1024; o <<= 1) {
        __syncthreads();
        int t = (threadIdx.x >= o) ? s[threadIdx.x - o] : 0;
        __syncthreads();
        s[threadIdx.x] += t;
    }
    __syncthreads();
    if (threadIdx.x < NB) {
        int incl = s[threadIdx.x];
        offsets[slot * 784 + threadIdx.x + 1] = incl;
        cursor[slot * NB + threadIdx.x] = incl - v;
    }
    if (threadIdx.x == 0) offsets[slot * 784] = 0;
}

// ---------------- fill: 1024 threads (16 waves) for latency hiding
// rec = src[15:0] | dstLocal[21:16] | valq[31:22]
__global__ __launch_bounds__(1024) void fill_kernel(
    const int* __restrict__ esrc, const int* __restrict__ edst,
    const float* __restrict__ ev, int* __restrict__ cursor,
    unsigned int* __restrict__ recs)
{
    __shared__ int lh[NB];
    __shared__ int lbase[NB];
    const int slot = blockIdx.y;
    const size_t eb = (size_t)slot * EE;
    const int e0 = blockIdx.x * FT;

    for (int i = threadIdx.x; i < NB; i += 1024) lh[i] = 0;
    __syncthreads();
    for (int t = 0; t < FT; t += 1024) {
        int e = e0 + t + threadIdx.x;
        if (e < EE) atomicAdd(&lh[edst[eb + e] >> BSH], 1);
    }
    __syncthreads();
    for (int i = threadIdx.x; i < NB; i += 1024) {
        int c = lh[i];
        lbase[i] = c ? atomicAdd(&cursor[slot * NB + i], c) : 0;
        lh[i] = 0;    // reuse as local cursor
    }
    __syncthreads();
    for (int t = 0; t < FT; t += 1024) {
        int e = e0 + t + threadIdx.x;
        if (e < EE) {
            int d = edst[eb + e];
            int bk = d >> BSH;
            unsigned vq = (unsigned)__builtin_rintf(ev[eb + e] * 1023.0f);
            unsigned rec = (unsigned)esrc[eb + e] |
                           ((unsigned)(d & (BSZ - 1)) << 16) | (vq << 22);
            int p = lbase[bk] + atomicAdd(&lh[bk], 1);
            recs[eb + p] = rec;
        }
    }
}

// ---------------- sort: counting-sort each bucket by local dst; emit dofs
__global__ __launch_bounds__(256) void sort_kernel(
    unsigned int* __restrict__ recs, const int* __restrict__ offsets,
    int* __restrict__ dofs)
{
    __shared__ unsigned int lrec[SCAP];
    __shared__ int cnt[BSZ];
    __shared__ int cur[BSZ];
    const int bk = blockIdx.x, slot = blockIdx.y;
    unsigned int* rp = recs + (size_t)slot * EE;
    const int s = offsets[slot * 784 + bk], e = offsets[slot * 784 + bk + 1];
    const int n = e - s;

    for (int i = threadIdx.x; i < n; i += 256) lrec[i] = rp[s + i];
    if (threadIdx.x < BSZ) cnt[threadIdx.x] = 0;
    __syncthreads();
    for (int i = threadIdx.x; i < n; i += 256)
        atomicAdd(&cnt[(lrec[i] >> 16) & (BSZ - 1)], 1);
    __syncthreads();
    if (threadIdx.x < 64) {
        int v = cnt[threadIdx.x];
        int incl = v;
        #pragma unroll
        for (int o = 1; o < 64; o <<= 1) {
            int t = __shfl_up(incl, o, 64);
            if (threadIdx.x >= o) incl += t;
        }
        int excl = incl - v;
        cur[threadIdx.x] = excl;
        dofs[(size_t)slot * DSTR + bk * BSZ + threadIdx.x] = s + excl;
    }
    __syncthreads();
    for (int i = threadIdx.x; i < n; i += 256) {
        unsigned r = lrec[i];
        int p = atomicAdd(&cur[(r >> 16) & (BSZ - 1)], 1);
        rp[s + p] = r;
    }
}

// ---------------- gather core: acc += val * xb[src][lane2..lane2+1], ILP-8
#define DEQ (1.0f / 1023.0f)
#define LO16(u) __uint_as_float((u) << 16)
#define HI16(u) __uint_as_float((u) & 0xffff0000u)

__device__ __forceinline__ void gacc(const unsigned short* __restrict__ xb,
                                     const unsigned int* __restrict__ rp,
                                     unsigned i, unsigned e, unsigned lane2,
                                     float& acc0, float& acc1)
{
    for (; i + 8 <= e; i += 8) {
        unsigned q[8], u[8];
        #pragma unroll
        for (int j = 0; j < 8; ++j) q[j] = rp[i + j];
        #pragma unroll
        for (int j = 0; j < 8; ++j)
            u[j] = *(const unsigned*)(xb + (((q[j] & 0xffffu) << 7) + lane2));
        #pragma unroll
        for (int j = 0; j < 8; ++j) {
            float s = (float)(q[j] >> 22) * DEQ;
            acc0 = fmaf(s, LO16(u[j]), acc0);
            acc1 = fmaf(s, HI16(u[j]), acc1);
        }
    }
    if (i + 4 <= e) {
        unsigned q[4], u[4];
        #pragma unroll
        for (int j = 0; j < 4; ++j) q[j] = rp[i + j];
        #pragma unroll
        for (int j = 0; j < 4; ++j)
            u[j] = *(const unsigned*)(xb + (((q[j] & 0xffffu) << 7) + lane2));
        #pragma unroll
        for (int j = 0; j < 4; ++j) {
            float s = (float)(q[j] >> 22) * DEQ;
            acc0 = fmaf(s, LO16(u[j]), acc0);
            acc1 = fmaf(s, HI16(u[j]), acc1);
        }
        i += 4;
    }
    for (; i < e; ++i) {
        unsigned q0 = rp[i];
        unsigned u0 = *(const unsigned*)(xb + (((q0 & 0xffffu) << 7) + lane2));
        float s0 = (float)(q0 >> 22) * DEQ;
        acc0 = fmaf(s0, LO16(u0), acc0); acc1 = fmaf(s0, HI16(u0), acc1);
    }
}

// ---------------- gather: one wave per dst; both relations aggregate x rows
// writes agg[d][256] bf16 into the batch's d_out region (overwritten by GEMM)
__global__ __launch_bounds__(256) void gather_dual_kernel(
    const unsigned short* __restrict__ xb,
    const unsigned int* __restrict__ rp0, const unsigned int* __restrict__ rp1,
    const int* __restrict__ dofs0, const int* __restrict__ dofs1,
    unsigned short* __restrict__ agg)     // [NN][256] bf16
{
    const int d = blockIdx.x * 4 + (threadIdx.x >> 6);
    const unsigned lane2 = (threadIdx.x & 63) * 2;

    float a0 = 0.f, a1 = 0.f, b0 = 0.f, b1 = 0.f;
    gacc(xb, rp0, dofs0[d], dofs0[d + 1], lane2, a0, a1);
    gacc(xb, rp1, dofs1[d], dofs1[d + 1], lane2, b0, b1);

    unsigned short* row = agg + (size_t)d * 256;
    unsigned p0 = (unsigned)f2bf(a0) | ((unsigned)f2bf(a1) << 16);
    unsigned p1 = (unsigned)f2bf(b0) | ((unsigned)f2bf(b1) << 16);
    *(unsigned*)(row + lane2) = p0;
    *(unsigned*)(row + DD + lane2) = p1;
}

// ---------------- GEMM: out = relu(agg @ [W0;W1] + bias), K=256, IN PLACE.
// Block owns rows [row0,row0+128): reads them as bf16[256], writes f32[128].
// __syncthreads() separates last A-load from first store (intra-block race);
// no cross-block sharing of rows.
__global__ __launch_bounds__(256) void gemm_agg_kernel(
    const unsigned short* __restrict__ wt2,   // [128 n][256 k']
    const float* __restrict__ bias,
    float* __restrict__ outb)                 // [NN][128] f32 == agg region
{
    const unsigned short* agg = (const unsigned short*)outb;
    const int tid = threadIdx.x;
    const int w = tid >> 6, lane = tid & 63;
    const int wr = w >> 1, wc = w & 1;
    const int lq = lane >> 4, lr = lane & 15;
    const int row0 = blockIdx.x * 128;

    f32x4 acc[4][4] = {};

    #pragma unroll
    for (int ks = 0; ks < 8; ++ks) {
        const int k0 = ks * 32 + lq * 8;
        bf16x8 a[4], b[4];
        #pragma unroll
        for (int mi = 0; mi < 4; ++mi) {
            int row = row0 + wr * 64 + mi * 16 + lr;
            bf16x8 v = {};
            if (row < NN) v = *(const bf16x8*)(agg + (size_t)row * 256 + k0);
            a[mi] = v;
        }
        #pragma unroll
        for (int ni = 0; ni < 4; ++ni) {
            int n = wc * 64 + ni * 16 + lr;
            b[ni] = *(const bf16x8*)(wt2 + (size_t)n * 256 + k0);
        }
        #pragma unroll
        for (int mi = 0; mi < 4; ++mi)
            #pragma unroll
            for (int ni = 0; ni < 4; ++ni)
                acc[mi][ni] = __builtin_amdgcn_mfma_f32_16x16x32_bf16(
                    a[mi], b[ni], acc[mi][ni], 0, 0, 0);
    }

    __syncthreads();   // all A-loads retired before any in-place store

    #pragma unroll
    for (int mi = 0; mi < 4; ++mi) {
        #pragma unroll
        for (int q = 0; q < 4; ++q) {
            int row = row0 + wr * 64 + mi * 16 + lq * 4 + q;
            if (row < NN) {
                #pragma unroll
                for (int ni = 0; ni < 4; ++ni) {
                    int col = wc * 64 + ni * 16 + lr;
                    outb[(size_t)row * DD + col] =
                        fmaxf(acc[mi][ni][q] + bias[col], 0.f);
                }
            }
        }
    }
}

extern "C" void kernel_launch(void* const* d_in, const int* in_sizes, int n_in,
                              void* d_out, int out_size, void* d_ws, size_t ws_size,
                              hipStream_t stream) {
    const float* x     = (const float*)d_in[0];
    const float* eval_ = (const float*)d_in[1];
    const float* w     = (const float*)d_in[2];
    const float* bias  = (const float*)d_in[3];
    const int*   esrc  = (const int*)d_in[4];
    const int*   edst  = (const int*)d_in[5];
    float* out = (float*)d_out;

    char* ws = (char*)d_ws;
    unsigned short* xb      = (unsigned short*)(ws + XB_OFF);
    unsigned int*   recs    = (unsigned int*)(ws + REC_OFF);
    int*            counts  = (int*)(ws + CNT_OFF);
    int*            offsets = (int*)(ws + OFS_OFF);
    int*            cursor  = (int*)(ws + CUR_OFF);
    int*            dofs    = (int*)(ws + DOF_OFF);
    unsigned short* wt2     = (unsigned short*)(ws + WT_OFF);

    const dim3 blk(256);

    hipMemsetAsync(counts, 0, NSLOT * NB * sizeof(int), stream);
    wprep_kernel<<<(RR * DD * DD + 255) / 256, blk, 0, stream>>>(w, wt2);

    // CSR build (edge-only, once for all 4 slots)
    hist_kernel<<<dim3(128, NSLOT), blk, 0, stream>>>(edst, counts);
    scan_kernel<<<dim3(NSLOT), dim3(1024), 0, stream>>>(counts, offsets, cursor);
    fill_kernel<<<dim3(FBLK, NSLOT), dim3(1024), 0, stream>>>(
        esrc, edst, eval_, cursor, recs);
    sort_kernel<<<dim3(NB, NSLOT), blk, 0, stream>>>(recs, offsets, dofs);

    const dim3 cast_grid((NN * DD / 8 + 255) / 256);
    const dim3 gath_grid(NN / 4);
    const dim3 gemm_grid((NN + 127) / 128);

    for (int b = 0; b < BB; ++b) {
        const int s0 = b * RR, s1 = b * RR + 1;
        float* outb = out + (size_t)b * NN * DD;
        cast_kernel<<<cast_grid, blk, 0, stream>>>(x + (size_t)b * NN * DD, xb);
        gather_dual_kernel<<<gath_grid, blk, 0, stream>>>(
            xb, recs + (size_t)s0 * EE, recs + (size_t)s1 * EE,
            dofs + (size_t)s0 * DSTR, dofs + (size_t)s1 * DSTR,
            (unsigned short*)outb);
        gemm_agg_kernel<<<gemm_grid, blk, 0, stream>>>(wt2, bias, outb);
    }
}

// Round 10
// 184.686 us; speedup vs baseline: 1.6616x; 1.0354x over previous
//
#include <hip/hip_runtime.h>

#define BB 2
#define RR 2
#define NN 50000
#define EE 500000
#define DD 128
#define NSLOT 4
#define BSH 6                 // dst >> 6 -> bucket
#define BSZ 64                // dsts per bucket
#define NB 782                // ceil(NN/64)
#define FT 8192               // edges per fill block (keeps ~42B write runs)
#define FBLK 62               // ceil(EE/FT)
#define SCAP 2048             // sort LDS capacity (bucket mean 640, std 25)
#define DSTR 50048            // per-slot dofs stride

// ---- layout C (merged, 34,503,872 B <= 34,503,936 proven in round 6) ----
#define C_XB   0u             // bf16 xb[2][NN][DD]          25,600,000
#define C_REC  25600000u      // uint recs[NSLOT][EE]         8,000,000
#define C_CNT  33600000u      // int counts[NSLOT][NB]           12,512
#define C_OFS  33612512u      // int offsets[NSLOT][784]         12,544
#define C_CUR  33625056u      // int cursor[NSLOT][NB]           12,512
#define C_DOF  33637568u      // int dofs[NSLOT][DSTR]          800,768
#define C_WT   34438336u      // bf16 wt2[128 n][256 k']         65,536
#define C_TOTAL 34503872u

// ---- layout A (fallback, ~21.7 MB): single-batch xb ----
#define A_XB   0u
#define A_REC  12800000u
#define A_CNT  20800000u
#define A_OFS  20812544u
#define A_CUR  20825088u
#define A_DOF  20837632u
#define A_WT   21638400u

typedef __attribute__((ext_vector_type(8))) short bf16x8;
typedef __attribute__((ext_vector_type(4))) float f32x4;

__device__ __forceinline__ unsigned short f2bf(float f) {
    unsigned int u = __float_as_uint(f);
    u += 0x7fffu + ((u >> 16) & 1u);   // RNE
    return (unsigned short)(u >> 16);
}

__device__ __forceinline__ bf16x8 pack8(float4 a, float4 b) {
    bf16x8 r;
    r[0] = (short)f2bf(a.x); r[1] = (short)f2bf(a.y);
    r[2] = (short)f2bf(a.z); r[3] = (short)f2bf(a.w);
    r[4] = (short)f2bf(b.x); r[5] = (short)f2bf(b.y);
    r[6] = (short)f2bf(b.z); r[7] = (short)f2bf(b.w);
    return r;
}

// ---------------- W prep: w[R][K][N] f32 -> wt2[n][r*128+k] bf16
__global__ __launch_bounds__(256) void wprep_kernel(
    const float* __restrict__ w, unsigned short* __restrict__ wt2)
{
    int idx = blockIdx.x * 256 + threadIdx.x;       // RR*DD*DD = 32768
    if (idx >= RR * DD * DD) return;
    int r = idx >> 14;
    int k = (idx >> 7) & (DD - 1);
    int n = idx & (DD - 1);
    wt2[(size_t)n * 256 + r * DD + k] = f2bf(w[idx]);
}

// ---------------- cast x (batch = blockIdx.y) to bf16
__global__ __launch_bounds__(256) void cast_kernel(
    const float* __restrict__ x, unsigned short* __restrict__ xb)
{
    const size_t bo = (size_t)blockIdx.y * NN * DD;
    int i8 = (blockIdx.x * 256 + threadIdx.x) * 8;
    if (i8 >= NN * DD) return;
    float4 v0 = *(const float4*)&x[bo + i8];
    float4 v1 = *(const float4*)&x[bo + i8 + 4];
    *(bf16x8*)&xb[bo + i8] = pack8(v0, v1);
}

// ---------------- hist: LDS-privatized bucket histogram
__global__ __launch_bounds__(256) void hist_kernel(
    const int* __restrict__ edst, int* __restrict__ counts)
{
    __shared__ int h[NB];
    for (int i = threadIdx.x; i < NB; i += 256) h[i] = 0;
    __syncthreads();
    const int slot = blockIdx.y;
    const int* ed = edst + (size_t)slot * EE;
    for (int e = blockIdx.x * 256 + threadIdx.x; e < EE; e += 128 * 256)
        atomicAdd(&h[ed[e] >> BSH], 1);
    __syncthreads();
    int* c = counts + slot * NB;
    for (int i = threadIdx.x; i < NB; i += 256) {
        int v = h[i];
        if (v) atomicAdd(&c[i], v);
    }
}

// ---------------- scan: per-slot exclusive scan of NB bucket counts
__global__ __launch_bounds__(1024) void scan_kernel(
    const int* __restrict__ counts, int* __restrict__ offsets,
    int* __restrict__ cursor)
{
    __shared__ int s[1024];
    const int slot = blockIdx.x;
    int v = (threadIdx.x < NB) ? counts[slot * NB + threadIdx.x] : 0;
    s[threadIdx.x] = v;
    for (int o = 1; o < 1024; o <<= 1) {
        __syncthreads();
        int t = (threadIdx.x >= o) ? s[threadIdx.x - o] : 0;
        __syncthreads();
        s[threadIdx.x] += t;
    }
    __syncthreads();
    if (threadIdx.x < NB) {
        int incl = s[threadIdx.x];
        offsets[slot * 784 + threadIdx.x + 1] = incl;
        cursor[slot * NB + threadIdx.x] = incl - v;
    }
    if (threadIdx.x == 0) offsets[slot * 784] = 0;
}

// ---------------- fill: 1024 threads (16 waves) for latency hiding
// rec = src[15:0] | dstLocal[21:16] | valq[31:22]
__global__ __launch_bounds__(1024) void fill_kernel(
    const int* __restrict__ esrc, const int* __restrict__ edst,
    const float* __restrict__ ev, int* __restrict__ cursor,
    unsigned int* __restrict__ recs)
{
    __shared__ int lh[NB];
    __shared__ int lbase[NB];
    const int slot = blockIdx.y;
    const size_t eb = (size_t)slot * EE;
    const int e0 = blockIdx.x * FT;

    for (int i = threadIdx.x; i < NB; i += 1024) lh[i] = 0;
    __syncthreads();
    for (int t = 0; t < FT; t += 1024) {
        int e = e0 + t + threadIdx.x;
        if (e < EE) atomicAdd(&lh[edst[eb + e] >> BSH], 1);
    }
    __syncthreads();
    for (int i = threadIdx.x; i < NB; i += 1024) {
        int c = lh[i];
        lbase[i] = c ? atomicAdd(&cursor[slot * NB + i], c) : 0;
        lh[i] = 0;    // reuse as local cursor
    }
    __syncthreads();
    for (int t = 0; t < FT; t += 1024) {
        int e = e0 + t + threadIdx.x;
        if (e < EE) {
            int d = edst[eb + e];
            int bk = d >> BSH;
            unsigned vq = (unsigned)__builtin_rintf(ev[eb + e] * 1023.0f);
            unsigned rec = (unsigned)esrc[eb + e] |
                           ((unsigned)(d & (BSZ - 1)) << 16) | (vq << 22);
            int p = lbase[bk] + atomicAdd(&lh[bk], 1);
            recs[eb + p] = rec;
        }
    }
}

// ---------------- sort: counting-sort each bucket by local dst; emit dofs
__global__ __launch_bounds__(256) void sort_kernel(
    unsigned int* __restrict__ recs, const int* __restrict__ offsets,
    int* __restrict__ dofs)
{
    __shared__ unsigned int lrec[SCAP];
    __shared__ int cnt[BSZ];
    __shared__ int cur[BSZ];
    const int bk = blockIdx.x, slot = blockIdx.y;
    unsigned int* rp = recs + (size_t)slot * EE;
    const int s = offsets[slot * 784 + bk], e = offsets[slot * 784 + bk + 1];
    const int n = e - s;

    for (int i = threadIdx.x; i < n; i += 256) lrec[i] = rp[s + i];
    if (threadIdx.x < BSZ) cnt[threadIdx.x] = 0;
    __syncthreads();
    for (int i = threadIdx.x; i < n; i += 256)
        atomicAdd(&cnt[(lrec[i] >> 16) & (BSZ - 1)], 1);
    __syncthreads();
    if (threadIdx.x < 64) {
        int v = cnt[threadIdx.x];
        int incl = v;
        #pragma unroll
        for (int o = 1; o < 64; o <<= 1) {
            int t = __shfl_up(incl, o, 64);
            if (threadIdx.x >= o) incl += t;
        }
        int excl = incl - v;
        cur[threadIdx.x] = excl;
        dofs[(size_t)slot * DSTR + bk * BSZ + threadIdx.x] = s + excl;
    }
    __syncthreads();
    for (int i = threadIdx.x; i < n; i += 256) {
        unsigned r = lrec[i];
        int p = atomicAdd(&cur[(r >> 16) & (BSZ - 1)], 1);
        rp[s + p] = r;
    }
}

// ---------------- gather core: acc += val * xb[src][lane2..lane2+1], ILP-8
#define DEQ (1.0f / 1023.0f)
#define LO16(u) __uint_as_float((u) << 16)
#define HI16(u) __uint_as_float((u) & 0xffff0000u)

__device__ __forceinline__ void gacc(const unsigned short* __restrict__ xb,
                                     const unsigned int* __restrict__ rp,
                                     unsigned i, unsigned e, unsigned lane2,
                                     float& acc0, float& acc1)
{
    for (; i + 8 <= e; i += 8) {
        unsigned q[8], u[8];
        #pragma unroll
        for (int j = 0; j < 8; ++j) q[j] = rp[i + j];
        #pragma unroll
        for (int j = 0; j < 8; ++j)
            u[j] = *(const unsigned*)(xb + (((q[j] & 0xffffu) << 7) + lane2));
        #pragma unroll
        for (int j = 0; j < 8; ++j) {
            float s = (float)(q[j] >> 22) * DEQ;
            acc0 = fmaf(s, LO16(u[j]), acc0);
            acc1 = fmaf(s, HI16(u[j]), acc1);
        }
    }
    if (i + 4 <= e) {
        unsigned q[4], u[4];
        #pragma unroll
        for (int j = 0; j < 4; ++j) q[j] = rp[i + j];
        #pragma unroll
        for (int j = 0; j < 4; ++j)
            u[j] = *(const unsigned*)(xb + (((q[j] & 0xffffu) << 7) + lane2));
        #pragma unroll
        for (int j = 0; j < 4; ++j) {
            float s = (float)(q[j] >> 22) * DEQ;
            acc0 = fmaf(s, LO16(u[j]), acc0);
            acc1 = fmaf(s, HI16(u[j]), acc1);
        }
        i += 4;
    }
    for (; i < e; ++i) {
        unsigned q0 = rp[i];
        unsigned u0 = *(const unsigned*)(xb + (((q0 & 0xffffu) << 7) + lane2));
        float s0 = (float)(q0 >> 22) * DEQ;
        acc0 = fmaf(s0, LO16(u0), acc0); acc1 = fmaf(s0, HI16(u0), acc1);
    }
}

// ---------------- gather: wave per dst, batch = blockIdx.y.
// Reads xb[batch]; writes agg[d][256] bf16 into the batch's d_out region.
__global__ __launch_bounds__(256) void gather_dual_kernel(
    const unsigned short* __restrict__ xb,   // [.. ][NN][DD], batch-indexed
    const unsigned int* __restrict__ recs,   // slot-pair base
    const int* __restrict__ dofs,            // slot-pair base
    float* __restrict__ out)                 // batch-indexed
{
    const int y = blockIdx.y;
    const unsigned short* xbb = xb + (size_t)y * NN * DD;
    const unsigned int* rp0 = recs + (size_t)(y * 2) * EE;
    const unsigned int* rp1 = rp0 + EE;
    const int* d0p = dofs + (size_t)(y * 2) * DSTR;
    const int* d1p = d0p + DSTR;
    unsigned short* agg = (unsigned short*)(out + (size_t)y * NN * DD);

    const int d = blockIdx.x * 4 + (threadIdx.x >> 6);
    const unsigned lane2 = (threadIdx.x & 63) * 2;

    float a0 = 0.f, a1 = 0.f, b0 = 0.f, b1 = 0.f;
    gacc(xbb, rp0, d0p[d], d0p[d + 1], lane2, a0, a1);
    gacc(xbb, rp1, d1p[d], d1p[d + 1], lane2, b0, b1);

    unsigned short* row = agg + (size_t)d * 256;
    unsigned p0 = (unsigned)f2bf(a0) | ((unsigned)f2bf(a1) << 16);
    unsigned p1 = (unsigned)f2bf(b0) | ((unsigned)f2bf(b1) << 16);
    *(unsigned*)(row + lane2) = p0;
    *(unsigned*)(row + DD + lane2) = p1;
}

// ---------------- GEMM: out = relu(agg @ [W0;W1] + bias), K=256, IN PLACE.
// batch = blockIdx.y. Block owns rows [row0,row0+128): reads bf16[256]/row,
// writes f32[128]/row to the SAME bytes; __syncthreads() separates phases.
__global__ __launch_bounds__(256) void gemm_agg_kernel(
    const unsigned short* __restrict__ wt2,   // [128 n][256 k']
    const float* __restrict__ bias,
    float* __restrict__ out)                  // batch-indexed
{
    float* outb = out + (size_t)blockIdx.y * NN * DD;
    const unsigned short* agg = (const unsigned short*)outb;
    const int tid = threadIdx.x;
    const int w = tid >> 6, lane = tid & 63;
    const int wr = w >> 1, wc = w & 1;
    const int lq = lane >> 4, lr = lane & 15;
    const int row0 = blockIdx.x * 128;

    f32x4 acc[4][4] = {};

    #pragma unroll
    for (int ks = 0; ks < 8; ++ks) {
        const int k0 = ks * 32 + lq * 8;
        bf16x8 a[4], b[4];
        #pragma unroll
        for (int mi = 0; mi < 4; ++mi) {
            int row = row0 + wr * 64 + mi * 16 + lr;
            bf16x8 v = {};
            if (row < NN) v = *(const bf16x8*)(agg + (size_t)row * 256 + k0);
            a[mi] = v;
        }
        #pragma unroll
        for (int ni = 0; ni < 4; ++ni) {
            int n = wc * 64 + ni * 16 + lr;
            b[ni] = *(const bf16x8*)(wt2 + (size_t)n * 256 + k0);
        }
        #pragma unroll
        for (int mi = 0; mi < 4; ++mi)
            #pragma unroll
            for (int ni = 0; ni < 4; ++ni)
                acc[mi][ni] = __builtin_amdgcn_mfma_f32_16x16x32_bf16(
                    a[mi], b[ni], acc[mi][ni], 0, 0, 0);
    }

    __syncthreads();   // all A-loads retired before any in-place store

    #pragma unroll
    for (int mi = 0; mi < 4; ++mi) {
        #pragma unroll
        for (int q = 0; q < 4; ++q) {
            int row = row0 + wr * 64 + mi * 16 + lq * 4 + q;
            if (row < NN) {
                #pragma unroll
                for (int ni = 0; ni < 4; ++ni) {
                    int col = wc * 64 + ni * 16 + lr;
                    outb[(size_t)row * DD + col] =
                        fmaxf(acc[mi][ni][q] + bias[col], 0.f);
                }
            }
        }
    }
}

extern "C" void kernel_launch(void* const* d_in, const int* in_sizes, int n_in,
                              void* d_out, int out_size, void* d_ws, size_t ws_size,
                              hipStream_t stream) {
    const float* x     = (const float*)d_in[0];
    const float* eval_ = (const float*)d_in[1];
    const float* w     = (const float*)d_in[2];
    const float* bias  = (const float*)d_in[3];
    const int*   esrc  = (const int*)d_in[4];
    const int*   edst  = (const int*)d_in[5];
    float* out = (float*)d_out;

    const bool useC = (ws_size >= (size_t)C_TOTAL);   // constant per harness

    char* ws = (char*)d_ws;
    unsigned short* xb      = (unsigned short*)(ws + (useC ? C_XB : A_XB));
    unsigned int*   recs    = (unsigned int*)(ws + (useC ? C_REC : A_REC));
    int*            counts  = (int*)(ws + (useC ? C_CNT : A_CNT));
    int*            offsets = (int*)(ws + (useC ? C_OFS : A_OFS));
    int*            cursor  = (int*)(ws + (useC ? C_CUR : A_CUR));
    int*            dofs    = (int*)(ws + (useC ? C_DOF : A_DOF));
    unsigned short* wt2     = (unsigned short*)(ws + (useC ? C_WT : A_WT));

    const dim3 blk(256);
    const dim3 cast_grid((NN * DD / 8 + 255) / 256);
    const dim3 gath_grid(NN / 4);
    const dim3 gemm_grid((NN + 127) / 128);

    hipMemsetAsync(counts, 0, NSLOT * NB * sizeof(int), stream);
    wprep_kernel<<<(RR * DD * DD + 255) / 256, blk, 0, stream>>>(w, wt2);

    // CSR build (edge-only, once for all 4 slots)
    hist_kernel<<<dim3(128, NSLOT), blk, 0, stream>>>(edst, counts);
    scan_kernel<<<dim3(NSLOT), dim3(1024), 0, stream>>>(counts, offsets, cursor);
    fill_kernel<<<dim3(FBLK, NSLOT), dim3(1024), 0, stream>>>(
        esrc, edst, eval_, cursor, recs);
    sort_kernel<<<dim3(NB, NSLOT), blk, 0, stream>>>(recs, offsets, dofs);

    if (useC) {
        // both batches in single dispatches (grid.y = batch)
        cast_kernel<<<dim3(cast_grid.x, BB), blk, 0, stream>>>(x, xb);
        gather_dual_kernel<<<dim3(gath_grid.x, BB), blk, 0, stream>>>(
            xb, recs, dofs, out);
        gemm_agg_kernel<<<dim3(gemm_grid.x, BB), blk, 0, stream>>>(
            wt2, bias, out);
    } else {
        for (int b = 0; b < BB; ++b) {
            cast_kernel<<<cast_grid, blk, 0, stream>>>(
                x + (size_t)b * NN * DD, xb);
            gather_dual_kernel<<<gath_grid, blk, 0, stream>>>(
                xb, recs + (size_t)(b * 2) * EE, dofs + (size_t)(b * 2) * DSTR,
                out + (size_t)b * NN * DD);
            gemm_agg_kernel<<<gemm_grid, blk, 0, stream>>>(
                wt2, bias, out + (size_t)b * NN * DD);
        }
    }
}